// Round 1
// baseline (79.976 us; speedup 1.0000x reference)
//
#include <hip/hip_runtime.h>

#define NROWS 512
#define NLAB  16
#define TILE  16

// Zero the 16 per-label accumulators in workspace (harness poisons ws with 0xAA).
__global__ void auc_zero_ws(float* __restrict__ per_label) {
    if (threadIdx.x < NLAB) per_label[threadIdx.x] = 0.0f;
}

// One block per 16x16 tile of (i,j) row pairs. Each thread computes
// S[i,j] = sum_{c,d} relu(1 - yp[i,c] + yp[j,d]) and accumulates it into the
// per-label sums gated by posbit(i,l) && !posbit(j,l).
__global__ __launch_bounds__(256) void auc_pair_kernel(const int* __restrict__ yt,
                                                       const float* __restrict__ yp,
                                                       float* __restrict__ per_label) {
    __shared__ float ya[TILE][TILE];     // yp rows of the i-tile
    __shared__ float yb[TILE][TILE];     // yp rows of the j-tile, pre-biased by +1
    __shared__ unsigned posA[TILE];
    __shared__ unsigned posB[TILE];
    __shared__ float acc[NLAB];

    const int i0 = blockIdx.x * TILE;
    const int j0 = blockIdx.y * TILE;
    const int t = threadIdx.x;

    {
        const int r = t >> 4, c = t & 15;
        ya[r][c] = yp[(i0 + r) * NLAB + c];
        yb[r][c] = yp[(j0 + r) * NLAB + c] + 1.0f;
    }
    if (t < TILE) {
        unsigned pa = 0u, pb = 0u;
        #pragma unroll
        for (int l = 0; l < NLAB; ++l) {
            pa |= (yt[(i0 + t) * NLAB + l] == 1) ? (1u << l) : 0u;
            pb |= (yt[(j0 + t) * NLAB + l] == 1) ? (1u << l) : 0u;
        }
        posA[t] = pa;
        posB[t] = pb;
        acc[t] = 0.0f;
    }
    __syncthreads();

    const int ti = t >> 4;   // i-row within tile
    const int tj = t & 15;   // j-row within tile

    // Pull both rows into registers; LDS reads are broadcast-heavy and cheap.
    float a[TILE], b[TILE];
    #pragma unroll
    for (int c = 0; c < TILE; ++c) a[c] = ya[ti][c];
    #pragma unroll
    for (int d = 0; d < TILE; ++d) b[d] = yb[tj][d];

    float S = 0.0f;
    #pragma unroll
    for (int d = 0; d < TILE; ++d) {
        #pragma unroll
        for (int c = 0; c < TILE; ++c) {
            S += fmaxf(b[d] - a[c], 0.0f);
        }
    }

    // pos row i AND neg row j per label
    unsigned bits = posA[ti] & ~posB[tj];
    while (bits) {
        const int l = __ffs(bits) - 1;
        bits &= bits - 1;
        atomicAdd(&acc[l], S);
    }
    __syncthreads();

    if (t < NLAB) atomicAdd(&per_label[t], acc[t]);
}

// Single block: count n_pos per label, apply the dynamic weight, reduce to scalar.
__global__ __launch_bounds__(512) void auc_finalize(const int* __restrict__ yt,
                                                    const float* __restrict__ per_label,
                                                    float* __restrict__ out) {
    __shared__ int cnt[NLAB];
    const int t = threadIdx.x;
    if (t < NLAB) cnt[t] = 0;
    __syncthreads();

    #pragma unroll
    for (int l = 0; l < NLAB; ++l) {
        if (yt[t * NLAB + l] == 1) atomicAdd(&cnt[l], 1);
    }
    __syncthreads();

    if (t == 0) {
        double loss = 0.0;
        for (int l = 0; l < NLAB; ++l) {
            const int np_ = cnt[l];
            const int nn_ = NROWS - np_;   // mn = 1 - mp, so n_neg = B - n_pos
            if (np_ > 0 && nn_ > 0) {
                const double prod = (double)np_ * (double)nn_;
                const double denom = prod * prod * (double)(NLAB * NLAB);
                loss += (double)per_label[l] / denom;
            }
        }
        out[0] = (float)loss;
    }
}

extern "C" void kernel_launch(void* const* d_in, const int* in_sizes, int n_in,
                              void* d_out, int out_size, void* d_ws, size_t ws_size,
                              hipStream_t stream) {
    const int* y_true = (const int*)d_in[0];
    const float* y_pred = (const float*)d_in[1];
    float* out = (float*)d_out;
    float* per_label = (float*)d_ws;   // 16 floats

    auc_zero_ws<<<1, 64, 0, stream>>>(per_label);

    dim3 grid(NROWS / TILE, NROWS / TILE);   // 32 x 32 = 1024 blocks
    auc_pair_kernel<<<grid, 256, 0, stream>>>(y_true, y_pred, per_label);

    auc_finalize<<<1, NROWS, 0, stream>>>(y_true, per_label, out);
}

// Round 2
// 69.213 us; speedup vs baseline: 1.1555x; 1.1555x over previous
//
#include <hip/hip_runtime.h>

#define NROWS 512
#define NLAB  16
#define TILE  16
#define NBLK  ((NROWS / TILE) * (NROWS / TILE))   // 1024 tile-blocks

// One block per 16x16 tile of (i,j) row pairs. Each thread computes
// S[i,j] = sum_{c,d} relu(1 - yp[i,c] + yp[j,d]) and accumulates it into
// 16 per-label LDS accumulators gated by posbit(i,l) && !posbit(j,l).
// Block partials go to ws (no global atomics, no pre-zeroing needed).
__global__ __launch_bounds__(256) void auc_pair_kernel(const int* __restrict__ yt,
                                                       const float* __restrict__ yp,
                                                       float* __restrict__ partial) {
    __shared__ float ya[TILE][TILE];     // yp rows of the i-tile
    __shared__ float yb[TILE][TILE];     // yp rows of the j-tile, pre-biased by +1
    __shared__ unsigned posA[TILE];
    __shared__ unsigned posB[TILE];
    __shared__ float acc[NLAB];

    const int i0 = blockIdx.x * TILE;
    const int j0 = blockIdx.y * TILE;
    const int t = threadIdx.x;

    {
        const int r = t >> 4, c = t & 15;
        ya[r][c] = yp[(i0 + r) * NLAB + c];
        yb[r][c] = yp[(j0 + r) * NLAB + c] + 1.0f;
    }
    if (t < TILE) {
        unsigned pa = 0u, pb = 0u;
        #pragma unroll
        for (int l = 0; l < NLAB; ++l) {
            pa |= (yt[(i0 + t) * NLAB + l] == 1) ? (1u << l) : 0u;
            pb |= (yt[(j0 + t) * NLAB + l] == 1) ? (1u << l) : 0u;
        }
        posA[t] = pa;
        posB[t] = pb;
        acc[t] = 0.0f;
    }
    __syncthreads();

    const int ti = t >> 4;   // i-row within tile
    const int tj = t & 15;   // j-row within tile

    float a[TILE], b[TILE];
    #pragma unroll
    for (int c = 0; c < TILE; ++c) a[c] = ya[ti][c];
    #pragma unroll
    for (int d = 0; d < TILE; ++d) b[d] = yb[tj][d];

    float S = 0.0f;
    #pragma unroll
    for (int d = 0; d < TILE; ++d) {
        #pragma unroll
        for (int c = 0; c < TILE; ++c) {
            S += fmaxf(b[d] - a[c], 0.0f);
        }
    }

    // pos row i AND neg row j per label -> scatter into block-local LDS accums
    unsigned bits = posA[ti] & ~posB[tj];
    while (bits) {
        const int l = __ffs(bits) - 1;
        bits &= bits - 1;
        atomicAdd(&acc[l], S);
    }
    __syncthreads();

    const int blk = blockIdx.y * gridDim.x + blockIdx.x;
    if (t < NLAB) partial[blk * NLAB + t] = acc[t];
}

// One block, 256 threads: reduce 1024x16 partials, count n_pos per label,
// apply the dynamic weight, write the scalar loss.
__global__ __launch_bounds__(256) void auc_reduce_finalize(const int* __restrict__ yt,
                                                           const float* __restrict__ partial,
                                                           float* __restrict__ out) {
    __shared__ float lsum[16][NLAB];
    __shared__ int lcnt[16][NLAB];
    __shared__ float per_label[NLAB];

    const int t = threadIdx.x;
    const int lab = t & 15;
    const int grp = t >> 4;   // 0..15

    // Each thread sums 64 block-partials for its label (stride-16 groups).
    float s = 0.0f;
    for (int k = 0; k < NBLK / 16; ++k) {
        s += partial[(grp + 16 * k) * NLAB + lab];
    }
    lsum[grp][lab] = s;

    // Each thread counts positives for its label over 32 rows.
    int c = 0;
    for (int k = 0; k < NROWS / 16; ++k) {
        c += (yt[(grp + 16 * k) * NLAB + lab] == 1) ? 1 : 0;
    }
    lcnt[grp][lab] = c;
    __syncthreads();

    if (t < NLAB) {
        float ps = 0.0f;
        int pc = 0;
        #pragma unroll
        for (int g = 0; g < 16; ++g) {
            ps += lsum[g][t];
            pc += lcnt[g][t];
        }
        per_label[t] = ps;
        lcnt[0][t] = pc;
    }
    __syncthreads();

    if (t == 0) {
        double loss = 0.0;
        #pragma unroll
        for (int l = 0; l < NLAB; ++l) {
            const int np_ = lcnt[0][l];
            const int nn_ = NROWS - np_;   // mn = 1 - mp
            if (np_ > 0 && nn_ > 0) {
                const double prod = (double)np_ * (double)nn_;
                const double denom = prod * prod * (double)(NLAB * NLAB);
                loss += (double)per_label[l] / denom;
            }
        }
        out[0] = (float)loss;
    }
}

extern "C" void kernel_launch(void* const* d_in, const int* in_sizes, int n_in,
                              void* d_out, int out_size, void* d_ws, size_t ws_size,
                              hipStream_t stream) {
    const int* y_true = (const int*)d_in[0];
    const float* y_pred = (const float*)d_in[1];
    float* out = (float*)d_out;
    float* partial = (float*)d_ws;   // NBLK*NLAB floats = 64 KB

    dim3 grid(NROWS / TILE, NROWS / TILE);   // 32 x 32 = 1024 blocks
    auc_pair_kernel<<<grid, 256, 0, stream>>>(y_true, y_pred, partial);

    auc_reduce_finalize<<<1, 256, 0, stream>>>(y_true, partial, out);
}